// Round 1
// baseline (264.671 us; speedup 1.0000x reference)
//
#include <hip/hip_runtime.h>
#include <hip/hip_bf16.h>

// Shapes: B=128, T=16, L=32, D=256, H=8, E=V=64. TL = T*L = 512.
// d_out layout (floats): [0, 4194304) attn_output (B,T,L,64)
//                        [4194304, 71303168) scores (T,L,H,128,128)
// Tricks:
//  - K0 parks Wt (bf16, [3][512][256]) at the start of the attn region.
//  - K1 packs Q[128][64],K[128][64],V[128][64] bf16 tiles into the first
//    48 KB of each 64 KB (t,l,h) scores slot; K2 reads them and then
//    overwrites the slot with the fp32 scores. No d_ws usage at all.

using bf16x8 = __attribute__((ext_vector_type(8))) __bf16;
using f32x4  = __attribute__((ext_vector_type(4))) float;

__device__ __forceinline__ f32x4 mfma16(bf16x8 a, bf16x8 b, f32x4 c) {
  return __builtin_amdgcn_mfma_f32_16x16x32_bf16(a, b, c, 0, 0, 0);
}

// ---------------- K0: W (256,8,64) fp32 -> Wt[mat][col=512][d=256] bf16 ----
__global__ __launch_bounds__(512) void k0_wt(const float* __restrict__ Wq,
                                             const float* __restrict__ Wk,
                                             const float* __restrict__ Wv,
                                             __bf16* __restrict__ Wt) {
  int f   = blockIdx.x * 512 + threadIdx.x;   // 96*512 = 49152 threads
  int mat = f >> 14;
  int rem = f & 16383;
  int d8  = rem >> 9;          // 0..31  (octet of d)
  int col = rem & 511;         // 0..511 (h*64+e)
  const float* W = (mat == 0) ? Wq : (mat == 1) ? Wk : Wv;
  bf16x8 v;
#pragma unroll
  for (int i = 0; i < 8; ++i) v[i] = (__bf16)W[(d8 * 8 + i) * 512 + col];
  *(bf16x8*)(Wt + mat * 131072 + col * 256 + d8 * 8) = v;
}

// ---------------- K1: projections ----------------------------------------
// block = (t,l). LDS: x[128][256] bf16 swz (64KB) + wt[64][256] bf16 swz (32KB)
__global__ __launch_bounds__(512) void k1_proj(const float* __restrict__ xq,
                                               const float* __restrict__ xk,
                                               const float* __restrict__ xv,
                                               const __bf16* __restrict__ Wt,
                                               __bf16* __restrict__ qkv) {
  __shared__ char smem[98304];
  const int tid  = threadIdx.x;
  const int tl   = blockIdx.x;
  const int lane = tid & 63, w = tid >> 6;
  const int lrow = lane & 15, lk = lane >> 4;
  const int rs = w >> 1, cs = w & 1;           // wave tile: rows 32*rs, cols 32*cs
  const f32x4 z4 = {0.f, 0.f, 0.f, 0.f};

  for (int m = 0; m < 3; ++m) {
    const float* xm = (m == 0) ? xq : (m == 1) ? xk : xv;
    __syncthreads();  // previous matrix's compute done before restaging x
#pragma unroll
    for (int i = 0; i < 8; ++i) {               // stage x slice, bf16, swizzled
      int c = i * 512 + tid;
      int row = c >> 5, sl = c & 31;
      const float* g = xm + (size_t)row * 131072 + (size_t)tl * 256 + sl * 8;
      float4 f0 = *(const float4*)g;
      float4 f1 = *(const float4*)(g + 4);
      bf16x8 v;
      v[0] = (__bf16)f0.x; v[1] = (__bf16)f0.y; v[2] = (__bf16)f0.z; v[3] = (__bf16)f0.w;
      v[4] = (__bf16)f1.x; v[5] = (__bf16)f1.y; v[6] = (__bf16)f1.z; v[7] = (__bf16)f1.w;
      *(bf16x8*)(smem + row * 512 + ((sl ^ (row & 7)) << 4)) = v;
    }
    for (int h = 0; h < 8; ++h) {
      __syncthreads();  // x ready (first h) / previous wt reads done
#pragma unroll
      for (int i = 0; i < 4; ++i) {             // stage Wt tile [64][256]
        int c = i * 512 + tid;
        int wrow = c >> 5, sl = c & 31;
        uint4 val = *(const uint4*)(Wt + (size_t)(m * 512 + h * 64 + wrow) * 256 + sl * 8);
        *(uint4*)(smem + 65536 + wrow * 512 + ((sl ^ (wrow & 7)) << 4)) = val;
      }
      __syncthreads();

      f32x4 acc[2][2];
#pragma unroll
      for (int ri = 0; ri < 2; ++ri)
#pragma unroll
        for (int ci = 0; ci < 2; ++ci) acc[ri][ci] = z4;

#pragma unroll
      for (int kk = 0; kk < 8; ++kk) {
        int koff = lk * 16 + kk * 64;
        bf16x8 a[2], b[2];
#pragma unroll
        for (int ri = 0; ri < 2; ++ri) {
          int row = rs * 32 + ri * 16 + lrow;
          a[ri] = *(const bf16x8*)(smem + row * 512 + (koff ^ ((row & 7) << 4)));
        }
#pragma unroll
        for (int ci = 0; ci < 2; ++ci) {
          int col = cs * 32 + ci * 16 + lrow;
          b[ci] = *(const bf16x8*)(smem + 65536 + col * 512 + (koff ^ ((col & 7) << 4)));
        }
#pragma unroll
        for (int ri = 0; ri < 2; ++ri)
#pragma unroll
          for (int ci = 0; ci < 2; ++ci)
            acc[ri][ci] = mfma16(a[ri], b[ci], acc[ri][ci]);
      }

      __bf16* dst = qkv + (size_t)(tl * 8 + h) * 32768 + m * 8192;
#pragma unroll
      for (int ri = 0; ri < 2; ++ri)
#pragma unroll
        for (int ci = 0; ci < 2; ++ci)
#pragma unroll
          for (int r = 0; r < 4; ++r) {
            int brow = rs * 32 + ri * 16 + lk * 4 + r;
            int e    = cs * 32 + ci * 16 + lrow;
            dst[brow * 64 + e] = (__bf16)acc[ri][ci][r];
          }
    }
  }
}

// ---------------- K2: scores + softmax + PV + head mix --------------------
// block = (t,l), loops h. LDS: q 16K | k 16K | v^T 16K | p 8*4K = 80 KB
__global__ __launch_bounds__(512) void k2_attn(const float* __restrict__ mask,
                                               const float* __restrict__ w_head,
                                               float* out_base) {
  __shared__ char smem[81920];
  const int tid  = threadIdx.x;
  const int tl   = blockIdx.x;
  const int lane = tid & 63, w = tid >> 6;
  const int lrow = lane & 15, lk = lane >> 4;
  const f32x4 z4 = {0.f, 0.f, 0.f, 0.f};

  float* scores = out_base + 4194304;

  // per-lane mask values (reused for all 8 heads)
  float mreg[8][4];
#pragma unroll
  for (int ct = 0; ct < 8; ++ct)
#pragma unroll
    for (int r = 0; r < 4; ++r)
      mreg[ct][r] = mask[(w * 16 + lk * 4 + r) * 128 + ct * 16 + lrow];

  f32x4 oacc[4];
#pragma unroll
  for (int i = 0; i < 4; ++i) oacc[i] = z4;

  for (int h = 0; h < 8; ++h) {
    const __bf16* slot = (const __bf16*)scores + (size_t)(tl * 8 + h) * 32768;
    float wh = w_head[h];
    __syncthreads();  // previous head's LDS reads done
#pragma unroll
    for (int i = 0; i < 2; ++i) {
      int c = i * 512 + tid;
      int row = c >> 3, sl = c & 7;
      uint4 qv = *(const uint4*)(slot + row * 64 + sl * 8);
      *(uint4*)(smem + row * 128 + ((sl ^ (row & 7)) << 4)) = qv;
      uint4 kv = *(const uint4*)(slot + 8192 + row * 64 + sl * 8);
      *(uint4*)(smem + 16384 + row * 128 + ((sl ^ (row & 7)) << 4)) = kv;
      bf16x8 vv = *(const bf16x8*)(slot + 16384 + row * 64 + sl * 8);
#pragma unroll
      for (int j = 0; j < 8; ++j) {            // transpose V on stage
        int e = sl * 8 + j;
        *(__bf16*)(smem + 32768 + e * 256 + ((row * 2) ^ ((e & 7) << 4))) = vv[j];
      }
    }
    __syncthreads();

    // S = Q K^T  (wave strip = 16 rows x 128 cols)
    int arow = w * 16 + lrow;
    const char* qb = smem + arow * 128;
    int aswz = (arow & 7) << 4;
    bf16x8 a0 = *(const bf16x8*)(qb + ((lk * 16 + 0) ^ aswz));
    bf16x8 a1 = *(const bf16x8*)(qb + ((lk * 16 + 64) ^ aswz));
    f32x4 sacc[8];
#pragma unroll
    for (int ct = 0; ct < 8; ++ct) {
      int bcol = ct * 16 + lrow;
      const char* kb = smem + 16384 + bcol * 128;
      int bswz = (bcol & 7) << 4;
      bf16x8 b0 = *(const bf16x8*)(kb + ((lk * 16 + 0) ^ bswz));
      bf16x8 b1 = *(const bf16x8*)(kb + ((lk * 16 + 64) ^ bswz));
      sacc[ct] = mfma16(a0, b0, z4);
      sacc[ct] = mfma16(a1, b1, sacc[ct]);
    }

    // scale * mask, emit scores
    float* srow = scores + (size_t)(tl * 8 + h) * 16384;
#pragma unroll
    for (int ct = 0; ct < 8; ++ct)
#pragma unroll
      for (int r = 0; r < 4; ++r) {
        float s = sacc[ct][r] * 0.125f * mreg[ct][r];
        sacc[ct][r] = s;
        srow[(w * 16 + lk * 4 + r) * 128 + ct * 16 + lrow] = s;
      }

    // row softmax (row lives in one 16-lane group), fold w_head, P -> LDS
#pragma unroll
    for (int r = 0; r < 4; ++r) {
      float mx = sacc[0][r];
#pragma unroll
      for (int ct = 1; ct < 8; ++ct) mx = fmaxf(mx, sacc[ct][r]);
      mx = fmaxf(mx, __shfl_xor(mx, 1));
      mx = fmaxf(mx, __shfl_xor(mx, 2));
      mx = fmaxf(mx, __shfl_xor(mx, 4));
      mx = fmaxf(mx, __shfl_xor(mx, 8));
      float sum = 0.f;
#pragma unroll
      for (int ct = 0; ct < 8; ++ct) {
        float p = __expf(sacc[ct][r] - mx);
        sacc[ct][r] = p;
        sum += p;
      }
      sum += __shfl_xor(sum, 1);
      sum += __shfl_xor(sum, 2);
      sum += __shfl_xor(sum, 4);
      sum += __shfl_xor(sum, 8);
      float fct = wh / sum;
      int row16 = lk * 4 + r;
      char* pb = smem + 49152 + w * 4096 + row16 * 256;
      int pswz = (row16 & 7) << 4;
#pragma unroll
      for (int ct = 0; ct < 8; ++ct) {
        int col = ct * 16 + lrow;
        *(__bf16*)(pb + ((col * 2) ^ pswz)) = (__bf16)(sacc[ct][r] * fct);
      }
    }

    // PV: out_acc += (wh*P) @ V   (accumulates across heads)
    const char* pab = smem + 49152 + w * 4096 + lrow * 256;
    int paswz = (lrow & 7) << 4;
    bf16x8 pa[4];
#pragma unroll
    for (int kk = 0; kk < 4; ++kk)
      pa[kk] = *(const bf16x8*)(pab + ((lk * 16 + kk * 64) ^ paswz));
#pragma unroll
    for (int ct2 = 0; ct2 < 4; ++ct2) {
      int ecol = ct2 * 16 + lrow;
      const char* vb = smem + 32768 + ecol * 256;
      int vswz = (ecol & 7) << 4;
#pragma unroll
      for (int kk = 0; kk < 4; ++kk) {
        bf16x8 b = *(const bf16x8*)(vb + ((lk * 16 + kk * 64) ^ vswz));
        oacc[ct2] = mfma16(pa[kk], b, oacc[ct2]);
      }
    }
  }

  // attn_output[b,t,l,e] : ((b*T+t)*L+l)*64 + e = (b*512 + tl)*64 + e
#pragma unroll
  for (int ct2 = 0; ct2 < 4; ++ct2)
#pragma unroll
    for (int r = 0; r < 4; ++r) {
      int brow = w * 16 + lk * 4 + r;
      int e    = ct2 * 16 + lrow;
      out_base[(size_t)(brow * 512 + tl) * 64 + e] = oacc[ct2][r];
    }
}

extern "C" void kernel_launch(void* const* d_in, const int* in_sizes, int n_in,
                              void* d_out, int out_size, void* d_ws, size_t ws_size,
                              hipStream_t stream) {
  const float* q    = (const float*)d_in[0];
  const float* k    = (const float*)d_in[1];
  const float* v    = (const float*)d_in[2];
  const float* mask = (const float*)d_in[3];
  const float* Wq   = (const float*)d_in[4];
  const float* Wk   = (const float*)d_in[5];
  const float* Wv   = (const float*)d_in[6];
  const float* wh   = (const float*)d_in[7];
  float* out = (float*)d_out;

  __bf16* Wt  = (__bf16*)out;                  // 786 KB, inside attn region
  __bf16* qkv = (__bf16*)(out + 4194304);      // packed into scores slots

  hipLaunchKernelGGL(k0_wt,   dim3(96),  dim3(512), 0, stream, Wq, Wk, Wv, Wt);
  hipLaunchKernelGGL(k1_proj, dim3(512), dim3(512), 0, stream, q, k, v, Wt, qkv);
  hipLaunchKernelGGL(k2_attn, dim3(512), dim3(512), 0, stream, mask, wh, out);
}

// Round 2
// 235.221 us; speedup vs baseline: 1.1252x; 1.1252x over previous
//
#include <hip/hip_runtime.h>
#include <hip/hip_bf16.h>

// Shapes: B=128, T=16, L=32, D=256, H=8, E=V=64. TL = T*L = 512.
// d_out layout (floats): [0, 4194304) attn_output (B,T,L,64)
//                        [4194304, 71303168) scores (T,L,H,128,128)
//  - K0 parks Wt (bf16, [3][512][256]) at the start of the attn region.
//  - K1 packs Q[128][64],K[128][64],V[128][64] bf16 tiles into the first
//    48 KB of each 64 KB (t,l,h) scores slot; K2 reads them and then
//    overwrites the slot with the fp32 scores. No d_ws usage at all.

using bf16x8 = __attribute__((ext_vector_type(8))) __bf16;
using f32x4  = __attribute__((ext_vector_type(4))) float;

__device__ __forceinline__ f32x4 mfma16(bf16x8 a, bf16x8 b, f32x4 c) {
  return __builtin_amdgcn_mfma_f32_16x16x32_bf16(a, b, c, 0, 0, 0);
}

// ---------------- K0: W (256,8,64) fp32 -> Wt[mat][col=512][d=256] bf16 ----
__global__ __launch_bounds__(512) void k0_wt(const float* __restrict__ Wq,
                                             const float* __restrict__ Wk,
                                             const float* __restrict__ Wv,
                                             __bf16* __restrict__ Wt) {
  int f   = blockIdx.x * 512 + threadIdx.x;   // 96*512 = 49152 threads
  int mat = f >> 14;
  int rem = f & 16383;
  int d8  = rem >> 9;          // 0..31  (octet of d)
  int col = rem & 511;         // 0..511 (h*64+e)
  const float* W = (mat == 0) ? Wq : (mat == 1) ? Wk : Wv;
  bf16x8 v;
#pragma unroll
  for (int i = 0; i < 8; ++i) v[i] = (__bf16)W[(d8 * 8 + i) * 512 + col];
  *(bf16x8*)(Wt + mat * 131072 + col * 256 + d8 * 8) = v;
}

// ---------------- K1: projections (rewritten) -----------------------------
// block = (tl, m). LDS: x[128][256] bf16 swizzled = 64 KB -> 2 blocks/CU.
// ONE barrier. Wave w owns head h=w; B-fragments read straight from L2
// (Wt is 768 KB, L2-resident). Two 64x64 output passes, acc[4][4].
__global__ __launch_bounds__(512) void k1_proj(const float* __restrict__ xq,
                                               const float* __restrict__ xk,
                                               const float* __restrict__ xv,
                                               const __bf16* __restrict__ Wt,
                                               __bf16* __restrict__ qkv) {
  __shared__ char smem[65536];
  const int tid  = threadIdx.x;
  const int tl   = blockIdx.x;
  const int m    = blockIdx.y;
  const int lane = tid & 63, w = tid >> 6;
  const int lrow = lane & 15, lk = lane >> 4;
  const f32x4 z4 = {0.f, 0.f, 0.f, 0.f};

  const float* xm = (m == 0) ? xq : (m == 1) ? xk : xv;

  // stage x slice [b=128][d=256] -> bf16, XOR-swizzled rows of 512 B
#pragma unroll
  for (int i = 0; i < 8; ++i) {
    int c = i * 512 + tid;
    int row = c >> 5, sl = c & 31;
    const float* g = xm + (size_t)row * 131072 + (size_t)tl * 256 + sl * 8;
    float4 f0 = *(const float4*)g;
    float4 f1 = *(const float4*)(g + 4);
    bf16x8 v;
    v[0] = (__bf16)f0.x; v[1] = (__bf16)f0.y; v[2] = (__bf16)f0.z; v[3] = (__bf16)f0.w;
    v[4] = (__bf16)f1.x; v[5] = (__bf16)f1.y; v[6] = (__bf16)f1.z; v[7] = (__bf16)f1.w;
    *(bf16x8*)(smem + row * 512 + ((sl ^ (row & 7)) << 4)) = v;
  }
  __syncthreads();

  const int h = w;                                  // wave <-> head
  const __bf16* wbase = Wt + (size_t)(m * 512 + h * 64) * 256;
  __bf16* dst = qkv + (size_t)(tl * 8 + h) * 32768 + m * 8192;

  for (int rh = 0; rh < 2; ++rh) {                  // row-half: 64 b-rows
    f32x4 acc[4][4];
#pragma unroll
    for (int ri = 0; ri < 4; ++ri)
#pragma unroll
      for (int ci = 0; ci < 4; ++ci) acc[ri][ci] = z4;

#pragma unroll
    for (int kk = 0; kk < 8; ++kk) {                // K = 8 x 32
      int koff = lk * 16 + kk * 64;                 // byte offset: k = kk*32+lk*8
      bf16x8 a[4], b[4];
#pragma unroll
      for (int ri = 0; ri < 4; ++ri) {
        int row = rh * 64 + ri * 16 + lrow;
        a[ri] = *(const bf16x8*)(smem + row * 512 + (koff ^ ((row & 7) << 4)));
      }
#pragma unroll
      for (int ci = 0; ci < 4; ++ci)                // from L2, 16 B/lane
        b[ci] = *(const bf16x8*)(wbase + (ci * 16 + lrow) * 256 + kk * 32 + lk * 8);
#pragma unroll
      for (int ri = 0; ri < 4; ++ri)
#pragma unroll
        for (int ci = 0; ci < 4; ++ci)
          acc[ri][ci] = mfma16(a[ri], b[ci], acc[ri][ci]);
    }

#pragma unroll
    for (int ri = 0; ri < 4; ++ri)
#pragma unroll
      for (int ci = 0; ci < 4; ++ci)
#pragma unroll
        for (int r = 0; r < 4; ++r) {
          int brow = rh * 64 + ri * 16 + lk * 4 + r;
          int e    = ci * 16 + lrow;
          dst[brow * 64 + e] = (__bf16)acc[ri][ci][r];
        }
  }
}

// ---------------- K2: scores + softmax + PV + head mix --------------------
// block = (t,l), loops h. LDS: q 16K | k 16K | v^T 16K | p 8*4K = 80 KB
__global__ __launch_bounds__(512) void k2_attn(const float* __restrict__ mask,
                                               const float* __restrict__ w_head,
                                               float* out_base) {
  __shared__ char smem[81920];
  const int tid  = threadIdx.x;
  const int tl   = blockIdx.x;
  const int lane = tid & 63, w = tid >> 6;
  const int lrow = lane & 15, lk = lane >> 4;
  const f32x4 z4 = {0.f, 0.f, 0.f, 0.f};

  float* scores = out_base + 4194304;

  // per-lane mask values (reused for all 8 heads)
  float mreg[8][4];
#pragma unroll
  for (int ct = 0; ct < 8; ++ct)
#pragma unroll
    for (int r = 0; r < 4; ++r)
      mreg[ct][r] = mask[(w * 16 + lk * 4 + r) * 128 + ct * 16 + lrow];

  f32x4 oacc[4];
#pragma unroll
  for (int i = 0; i < 4; ++i) oacc[i] = z4;

  for (int h = 0; h < 8; ++h) {
    const __bf16* slot = (const __bf16*)scores + (size_t)(tl * 8 + h) * 32768;
    float wh = w_head[h];
    __syncthreads();  // previous head's LDS reads done
#pragma unroll
    for (int i = 0; i < 2; ++i) {
      int c = i * 512 + tid;
      int row = c >> 3, sl = c & 7;
      uint4 qv = *(const uint4*)(slot + row * 64 + sl * 8);
      *(uint4*)(smem + row * 128 + ((sl ^ (row & 7)) << 4)) = qv;
      uint4 kv = *(const uint4*)(slot + 8192 + row * 64 + sl * 8);
      *(uint4*)(smem + 16384 + row * 128 + ((sl ^ (row & 7)) << 4)) = kv;
      bf16x8 vv = *(const bf16x8*)(slot + 16384 + row * 64 + sl * 8);
#pragma unroll
      for (int j = 0; j < 8; ++j) {            // transpose V on stage
        int e = sl * 8 + j;
        *(__bf16*)(smem + 32768 + e * 256 + ((row * 2) ^ ((e & 7) << 4))) = vv[j];
      }
    }
    __syncthreads();

    // S = Q K^T  (wave strip = 16 rows x 128 cols)
    int arow = w * 16 + lrow;
    const char* qb = smem + arow * 128;
    int aswz = (arow & 7) << 4;
    bf16x8 a0 = *(const bf16x8*)(qb + ((lk * 16 + 0) ^ aswz));
    bf16x8 a1 = *(const bf16x8*)(qb + ((lk * 16 + 64) ^ aswz));
    f32x4 sacc[8];
#pragma unroll
    for (int ct = 0; ct < 8; ++ct) {
      int bcol = ct * 16 + lrow;
      const char* kb = smem + 16384 + bcol * 128;
      int bswz = (bcol & 7) << 4;
      bf16x8 b0 = *(const bf16x8*)(kb + ((lk * 16 + 0) ^ bswz));
      bf16x8 b1 = *(const bf16x8*)(kb + ((lk * 16 + 64) ^ bswz));
      sacc[ct] = mfma16(a0, b0, z4);
      sacc[ct] = mfma16(a1, b1, sacc[ct]);
    }

    // scale * mask, emit scores
    float* srow = scores + (size_t)(tl * 8 + h) * 16384;
#pragma unroll
    for (int ct = 0; ct < 8; ++ct)
#pragma unroll
      for (int r = 0; r < 4; ++r) {
        float s = sacc[ct][r] * 0.125f * mreg[ct][r];
        sacc[ct][r] = s;
        srow[(w * 16 + lk * 4 + r) * 128 + ct * 16 + lrow] = s;
      }

    // row softmax (row lives in one 16-lane group), fold w_head, P -> LDS
#pragma unroll
    for (int r = 0; r < 4; ++r) {
      float mx = sacc[0][r];
#pragma unroll
      for (int ct = 1; ct < 8; ++ct) mx = fmaxf(mx, sacc[ct][r]);
      mx = fmaxf(mx, __shfl_xor(mx, 1));
      mx = fmaxf(mx, __shfl_xor(mx, 2));
      mx = fmaxf(mx, __shfl_xor(mx, 4));
      mx = fmaxf(mx, __shfl_xor(mx, 8));
      float sum = 0.f;
#pragma unroll
      for (int ct = 0; ct < 8; ++ct) {
        float p = __expf(sacc[ct][r] - mx);
        sacc[ct][r] = p;
        sum += p;
      }
      sum += __shfl_xor(sum, 1);
      sum += __shfl_xor(sum, 2);
      sum += __shfl_xor(sum, 4);
      sum += __shfl_xor(sum, 8);
      float fct = wh / sum;
      int row16 = lk * 4 + r;
      char* pb = smem + 49152 + w * 4096 + row16 * 256;
      int pswz = (row16 & 7) << 4;
#pragma unroll
      for (int ct = 0; ct < 8; ++ct) {
        int col = ct * 16 + lrow;
        *(__bf16*)(pb + ((col * 2) ^ pswz)) = (__bf16)(sacc[ct][r] * fct);
      }
    }

    // PV: out_acc += (wh*P) @ V   (accumulates across heads)
    const char* pab = smem + 49152 + w * 4096 + lrow * 256;
    int paswz = (lrow & 7) << 4;
    bf16x8 pa[4];
#pragma unroll
    for (int kk = 0; kk < 4; ++kk)
      pa[kk] = *(const bf16x8*)(pab + ((lk * 16 + kk * 64) ^ paswz));
#pragma unroll
    for (int ct2 = 0; ct2 < 4; ++ct2) {
      int ecol = ct2 * 16 + lrow;
      const char* vb = smem + 32768 + ecol * 256;
      int vswz = (ecol & 7) << 4;
#pragma unroll
      for (int kk = 0; kk < 4; ++kk) {
        bf16x8 b = *(const bf16x8*)(vb + ((lk * 16 + kk * 64) ^ vswz));
        oacc[ct2] = mfma16(pa[kk], b, oacc[ct2]);
      }
    }
  }

  // attn_output[b,t,l,e] : ((b*T+t)*L+l)*64 + e = (b*512 + tl)*64 + e
#pragma unroll
  for (int ct2 = 0; ct2 < 4; ++ct2)
#pragma unroll
    for (int r = 0; r < 4; ++r) {
      int brow = w * 16 + lk * 4 + r;
      int e    = ct2 * 16 + lrow;
      out_base[(size_t)(brow * 512 + tl) * 64 + e] = oacc[ct2][r];
    }
}

extern "C" void kernel_launch(void* const* d_in, const int* in_sizes, int n_in,
                              void* d_out, int out_size, void* d_ws, size_t ws_size,
                              hipStream_t stream) {
  const float* q    = (const float*)d_in[0];
  const float* k    = (const float*)d_in[1];
  const float* v    = (const float*)d_in[2];
  const float* mask = (const float*)d_in[3];
  const float* Wq   = (const float*)d_in[4];
  const float* Wk   = (const float*)d_in[5];
  const float* Wv   = (const float*)d_in[6];
  const float* wh   = (const float*)d_in[7];
  float* out = (float*)d_out;

  __bf16* Wt  = (__bf16*)out;                  // 786 KB, inside attn region
  __bf16* qkv = (__bf16*)(out + 4194304);      // packed into scores slots

  hipLaunchKernelGGL(k0_wt,   dim3(96),       dim3(512), 0, stream, Wq, Wk, Wv, Wt);
  hipLaunchKernelGGL(k1_proj, dim3(512, 3),   dim3(512), 0, stream, q, k, v, Wt, qkv);
  hipLaunchKernelGGL(k2_attn, dim3(512),      dim3(512), 0, stream, mask, wh, out);
}